// Round 15
// baseline (636.442 us; speedup 1.0000x reference)
//
#include <hip/hip_runtime.h>
#include <hip/hip_bf16.h>

typedef __hip_bfloat16 bf16;

#define BB 32
#define NN 50
#define DIN 2048
#define DD 512
#define PD 64
#define FF 80
#define GG 592
#define BN (BB*NN)      // 1600

// ---------------- ws layout (f32 words) ----------------
#define O_FLAG  0
#define O_MF    16
#define O_SS    1616
#define O_SO    3216
#define O_PS    4816
#define O_FS    107216
#define O_FO    235216
#define O_RL    363216     // k_ra output; ALSO k_x row-sum partials [1600x8] (dead until k_ra)
#define O_LG    491216     // full logits [1600x50] (f32 — edge threshold)
#define O_AN    571216
#define O_T     651216     // k_x slice-7 partials
#define O_X1    1598416
#define O_X2    2545616
#define O_WPRE  3364816
#define O_BPRE  4413392
#define O_GPRE  4413904
#define O_EPRE  4414416
#define O_WSUBJ 4414928
#define O_BSUBJ 4677072
#define O_WOBJ  4677584
#define O_BOBJ  4939728
#define O_WPS1  4940240
#define O_BPS1  4940752
#define O_GPS   4940816
#define O_EPS   4940880
#define O_WPS2  4940944
#define O_BPS2  4945040
#define O_WPR1  4945104
#define O_BPR1  4945616
#define O_GPR   4945680
#define O_EPR   4945744
#define O_WPR2  4945808
#define O_BPR2  4949904
#define O_WRS   4949968
#define O_BRS   4950544
#define O_WRF   4950560
#define O_BRF   4996640
#define O_WG1   4996736
#define O_BG1   5347200
#define O_WG2   5347792
#define O_BG2   5650896
#define O_WG3   5651408
#define O_BG3   5913552
#define O_FT    5914064    // per-pair feat [80000x80]; ALSO k_x partials + k_so ys scratch

#define PSLICE  819200

__device__ __forceinline__ float b2f(bf16 x){ return __bfloat162float(x); }

// Load logical f32 element i of an input buffer (bf16-pair reconstruction when F=1).
__device__ __forceinline__ float LDI(const bf16* p, size_t i, int f32m){
    if(f32m){
        bf16 a=p[2*i], b=p[2*i+1];
        unsigned short lo,hi;
        __builtin_memcpy(&lo,&a,2); __builtin_memcpy(&hi,&b,2);
        unsigned v=((unsigned)hi<<16)|(unsigned)lo;
        float f; __builtin_memcpy(&f,&v,4);
        return f;
    }
    return __bfloat162float(p[i]);
}

// ---------------- flag ----------------
__global__ void k_flag(const bf16* __restrict__ images, float* __restrict__ ws){
    __shared__ int cnt;
    if(threadIdx.x==0) cnt=0;
    __syncthreads();
    bf16 h=images[2*threadIdx.x];
    unsigned short u; __builtin_memcpy(&u,&h,2);
    unsigned e=(u>>7)&0xFF;
    int sane=((u&0x7FFF)==0 || (e>=0x70&&e<=0x85))?1:0;
    atomicAdd(&cnt,sane);
    __syncthreads();
    if(threadIdx.x==0) ws[O_FLAG]=(cnt<48)?1.f:0.f;
}

// ---------------- kw: convert all weights to f32 in ws ----------------
__device__ __forceinline__ void conv(const bf16* s, float* d, int n, int F, int i0, int st){
    for(int g=i0; g<n; g+=st) d[g]=LDI(s,(size_t)g,F);
}
__global__ void kw(const bf16* p0,const bf16* p1,const bf16* p2,const bf16* p3,
                   const bf16* p4,const bf16* p5,const bf16* p6,const bf16* p7,
                   const bf16* p8,const bf16* p9,const bf16* p10,const bf16* p11,
                   const bf16* p12,const bf16* p13,const bf16* p14,const bf16* p15,
                   const bf16* p16,const bf16* p17,const bf16* p18,const bf16* p19,
                   const bf16* p20,const bf16* p21,const bf16* p22,const bf16* p23,
                   const bf16* p24,const bf16* p25,const bf16* p26,const bf16* p27,
                   const bf16* p28,const bf16* p29, float* __restrict__ ws){
    int F=ws[O_FLAG]>0.5f;
    int i0=blockIdx.x*256+threadIdx.x, st=gridDim.x*256;
    conv(p0, ws+O_WPRE, 1048576,F,i0,st);
    conv(p1, ws+O_BPRE, 512,F,i0,st);
    conv(p2, ws+O_GPRE, 512,F,i0,st);
    conv(p3, ws+O_EPRE, 512,F,i0,st);
    conv(p4, ws+O_WSUBJ,262144,F,i0,st);
    conv(p5, ws+O_BSUBJ,512,F,i0,st);
    conv(p6, ws+O_WOBJ, 262144,F,i0,st);
    conv(p7, ws+O_BOBJ, 512,F,i0,st);
    conv(p8, ws+O_WPS1, 512,F,i0,st);
    conv(p9, ws+O_BPS1, 64,F,i0,st);
    conv(p10,ws+O_GPS,  64,F,i0,st);
    conv(p11,ws+O_EPS,  64,F,i0,st);
    conv(p12,ws+O_WPS2, 4096,F,i0,st);
    conv(p13,ws+O_BPS2, 64,F,i0,st);
    conv(p14,ws+O_WPR1, 512,F,i0,st);
    conv(p15,ws+O_BPR1, 64,F,i0,st);
    conv(p16,ws+O_GPR,  64,F,i0,st);
    conv(p17,ws+O_EPR,  64,F,i0,st);
    conv(p18,ws+O_WPR2, 4096,F,i0,st);
    conv(p19,ws+O_BPR2, 64,F,i0,st);
    conv(p20,ws+O_WRS,  576,F,i0,st);
    conv(p21,ws+O_BRS,  1,F,i0,st);
    conv(p22,ws+O_WRF,  46080,F,i0,st);
    conv(p23,ws+O_BRF,  80,F,i0,st);
    conv(p24,ws+O_WG1,  350464,F,i0,st);
    conv(p25,ws+O_BG1,  592,F,i0,st);
    conv(p26,ws+O_WG2,  303104,F,i0,st);
    conv(p27,ws+O_BG2,  512,F,i0,st);
    conv(p28,ws+O_WG3,  262144,F,i0,st);
    conv(p29,ws+O_BG3,  512,F,i0,st);
}

// ---------------- k_x: split-K x-GEMM (float4 weight loads) + row-sums + pos_self tail ----------------
__global__ void __launch_bounds__(256,4) k_x(const bf16* __restrict__ images,
                                             const bf16* __restrict__ sb,
                                             float* __restrict__ ws){
    int blk=blockIdx.x, t=threadIdx.x;
    int F=ws[O_FLAG]>0.5f;
    int wv=t>>6, ln=t&63;
    if(blk>=1600){
        // ---- pos_self: wave per row ----
        int r=(blk-1600)*4+wv;
        const float* w1=ws+O_WPS1;
        float acc=0.f;
        #pragma unroll
        for(int q=0;q<8;q++) acc+=LDI(sb,(size_t)r*8+q,F)*w1[q*PD+ln];
        float h1=fmaxf(acc+ws[O_BPS1+ln],0.f);
        float sm=0.f;
        for(int k=0;k<PD;k++) sm+=__shfl(h1,k,64);
        float mean=sm/PD;
        float v=0.f;
        for(int k=0;k<PD;k++){ float d=__shfl(h1,k,64)-mean; v+=d*d; }
        float rstd=rsqrtf(v/PD+1e-5f);
        float hn=(h1-mean)*rstd*ws[O_GPS+ln]+ws[O_EPS+ln];
        float a2=0.f;
        const float* w2=ws+O_WPS2;
        for(int k=0;k<PD;k++) a2+=__shfl(hn,k,64)*w2[k*PD+ln];
        ws[O_PS+(size_t)r*PD+ln]=fmaxf(a2+ws[O_BPS2+ln],0.f);
        return;
    }
    __shared__ float as[8*256];      // 8 KB
    __shared__ float rsum[4][8];
    int rg=blk>>3, ks=blk&7;
    int r0=rg*8, kbase=ks*256;
    float sv[8];
    #pragma unroll
    for(int row=0;row<8;row++){
        float v=LDI(images,(size_t)(r0+row)*DIN+kbase+t,F);
        as[row*256+t]=v;
        sv[row]=v;
    }
    #pragma unroll
    for(int row=0;row<8;row++){
        float s=sv[row];
        for(int m=32;m>0;m>>=1) s+=__shfl_xor(s,m,64);
        sv[row]=s;
    }
    if(ln==0){
        #pragma unroll
        for(int row=0;row<8;row++) rsum[wv][row]=sv[row];
    }
    __syncthreads();
    if(t<8){
        float s=rsum[0][t]+rsum[1][t]+rsum[2][t]+rsum[3][t];
        ws[O_RL+(size_t)(r0+t)*8+ks]=s;
    }
    const float* wP=ws+O_WPRE+(size_t)kbase*DD;
    int half=t>>7;                 // 0: rows 0-3, 1: rows 4-7
    int c4=(t&127)*4;
    int rowbase=half*4;
    float acc[4][4]={};
    for(int k0=0;k0<256;k0+=4){
        float4 w4[4];
        #pragma unroll
        for(int u=0;u<4;u++) w4[u]=*(const float4*)&wP[(size_t)(k0+u)*DD+c4];
        #pragma unroll
        for(int row=0;row<4;row++){
            float4 a0=*(const float4*)&as[(rowbase+row)*256+k0];
            const float* ap=(const float*)&a0;
            #pragma unroll
            for(int u=0;u<4;u++){
                const float* wp=(const float*)&w4[u];
                float ak=ap[u];
                acc[row][0]+=ak*wp[0]; acc[row][1]+=ak*wp[1];
                acc[row][2]+=ak*wp[2]; acc[row][3]+=ak*wp[3];
            }
        }
    }
    float* P=ws + ((ks<7)? (O_FT+(size_t)ks*PSLICE) : (size_t)O_T);
    #pragma unroll
    for(int row=0;row<4;row++){
        float4 o; o.x=acc[row][0]; o.y=acc[row][1]; o.z=acc[row][2]; o.w=acc[row][3];
        *(float4*)&P[(size_t)(r0+rowbase+row)*DD+c4]=o;
    }
}

// ---------------- k_xr: reduce partials + bias + relu + LN -> x; finalize mask ----------------
__global__ void __launch_bounds__(256,4) k_xr(float* __restrict__ ws, float* __restrict__ out){
    __shared__ float red[256];
    int blk=blockIdx.x, t=threadIdx.x;
    int r0=blk*4;
    if(t<4){
        int r=r0+t;
        float s=0.f;
        for(int ks=0;ks<8;ks++) s+=ws[O_RL+(size_t)r*8+ks];
        float mf=(s!=0.f)?1.f:0.f;
        ws[O_MF+r]=mf;
        out[(size_t)BB*2*NN*DD+r]=1.f-mf;
    }
    const float* bPre=ws+O_BPRE; const float* gPre=ws+O_GPRE; const float* ePre=ws+O_EPRE;
    int c0=t, c1=t+256;
    for(int row=0;row<4;row++){
        int r=r0+row;
        float y0=bPre[c0], y1=bPre[c1];
        for(int ks=0;ks<8;ks++){
            const float* P=ws + ((ks<7)? (O_FT+(size_t)ks*PSLICE) : (size_t)O_T);
            y0+=P[(size_t)r*DD+c0]; y1+=P[(size_t)r*DD+c1];
        }
        y0=fmaxf(y0,0.f); y1=fmaxf(y1,0.f);
        red[t]=y0+y1; __syncthreads();
        for(int o=128;o>0;o>>=1){ if(t<o) red[t]+=red[t+o]; __syncthreads(); }
        float mean=red[0]/DD; __syncthreads();
        float d0=y0-mean, d1=y1-mean;
        red[t]=d0*d0+d1*d1; __syncthreads();
        for(int o=128;o>0;o>>=1){ if(t<o) red[t]+=red[t+o]; __syncthreads(); }
        float rstd=rsqrtf(red[0]/DD+1e-5f);
        __syncthreads();
        float xv0=d0*rstd*gPre[c0]+ePre[c0];
        float xv1=d1*rstd*gPre[c1]+ePre[c1];
        size_t ob=((size_t)(r/NN)*2)*NN*DD+(size_t)(r%NN)*DD;
        out[ob+c0]=xv0; out[ob+c1]=xv1;
    }
}

// ---------------- k_so1: subj/obj GEMM, col-split, float4 LDS reads ----------------
__global__ void __launch_bounds__(256,4) k_so1(const float* __restrict__ out,
                                               float* __restrict__ ws){
    __shared__ float xs[4*DD];   // 8 KB
    __shared__ float mrow_s[4];
    int blk=blockIdx.x, t=threadIdx.x;
    int rg=blk>>2, mat=(blk>>1)&1, ch=blk&1;
    int r0=rg*4;
    for(int idx=t; idx<4*DD; idx+=256){
        int row=idx>>9, k=idx&511;
        int r=r0+row;
        xs[idx]=out[((size_t)(r/NN)*2)*NN*DD+(size_t)(r%NN)*DD+k];
    }
    if(t<4) mrow_s[t]=ws[O_MF+r0+t];
    __syncthreads();
    const float* W =ws+(mat?O_WOBJ:O_WSUBJ);
    const float* Bb=ws+(mat?O_BOBJ:O_BSUBJ);
    int c=ch*256+t;
    float acc[4]={0.f,0.f,0.f,0.f};
    for(int k0=0;k0<DD;k0+=8){
        float w[8];
        #pragma unroll
        for(int u=0;u<8;u++) w[u]=W[(size_t)(k0+u)*DD+c];
        #pragma unroll
        for(int row=0;row<4;row++){
            float4 a0=*(const float4*)&xs[row*DD+k0];
            float4 a1=*(const float4*)&xs[row*DD+k0+4];
            acc[row]+=a0.x*w[0]; acc[row]+=a0.y*w[1];
            acc[row]+=a0.z*w[2]; acc[row]+=a0.w*w[3];
            acc[row]+=a1.x*w[4]; acc[row]+=a1.y*w[5];
            acc[row]+=a1.z*w[6]; acc[row]+=a1.w*w[7];
        }
    }
    float* Y=ws+O_FT+(size_t)mat*PSLICE;
    #pragma unroll
    for(int row=0;row<4;row++)
        Y[(size_t)(r0+row)*DD+c]=fmaxf(acc[row]+Bb[c],0.f)*mrow_s[row];
}

// ---------------- k_so2: rs dots + rf projections, float4 LDS reads ----------------
__global__ void __launch_bounds__(256,4) k_so2(float* __restrict__ ws){
    __shared__ float yl[4][DD];  // 8 KB
    int blk=blockIdx.x, t=threadIdx.x, wv=t>>6, ln=t&63;
    int combo=blk*4+wv;
    int mat=combo&1, r=combo>>1;
    const float* Y=ws+O_FT+(size_t)mat*PSLICE+(size_t)r*DD;
    for(int k=ln;k<DD;k+=64) yl[wv][k]=Y[k];
    __syncthreads();
    const float* wRs=ws+O_WRS;
    float ps=0.f;
    for(int k=ln;k<DD;k+=64) ps+=yl[wv][k]*wRs[k];
    for(int m=32;m>0;m>>=1) ps+=__shfl_xor(ps,m,64);
    if(ln==0) ws[(mat?O_SO:O_SS)+r]=ps;
    const float* wRf=ws+O_WRF;
    float* dst=ws+(mat?O_FO:O_FS)+(size_t)r*FF;
    {
        float a=0.f;
        for(int k0=0;k0<DD;k0+=4){
            float4 y4=*(const float4*)&yl[wv][k0];
            a+=y4.x*wRf[(size_t)k0*FF+ln];
            a+=y4.y*wRf[(size_t)(k0+1)*FF+ln];
            a+=y4.z*wRf[(size_t)(k0+2)*FF+ln];
            a+=y4.w*wRf[(size_t)(k0+3)*FF+ln];
        }
        dst[ln]=a;
    }
    if(ln<16){
        int c=64+ln;
        float a=0.f;
        for(int k0=0;k0<DD;k0+=4){
            float4 y4=*(const float4*)&yl[wv][k0];
            a+=y4.x*wRf[(size_t)k0*FF+c];
            a+=y4.y*wRf[(size_t)(k0+1)*FF+c];
            a+=y4.z*wRf[(size_t)(k0+2)*FF+c];
            a+=y4.w*wRf[(size_t)(k0+3)*FF+c];
        }
        dst[c]=a;
    }
}

// ---------------- k_pair: R5 structure + barrier elision + phase overlap (77.7us) ----------------
#define PSTRIDE 68
#define ZROW(m) ((m)*PSTRIDE + (((m)>>3)<<2))

__global__ void __launch_bounds__(256,3) k_pair(const bf16* __restrict__ bbox,
                                                float* __restrict__ ws){
    __shared__ float zp[64*PSTRIDE+64];    // z, then pv (17.5 KB)
    __shared__ float wbuf[80*PSTRIDE];     // W2t [k][c], then WrfT [f][k] (21.25 KB)
    __shared__ float w1s[512];
    __shared__ float bbs[512];
    __shared__ float b1s[64], g1s[64], be1s[64], b2s[64], wrss[64];
    __shared__ float brfs[80];
    __shared__ float rowmi[64], rowmj[64], rowbase[64];
    __shared__ int   rowfb[64], rowps[64], rowdg[64];

    int t=threadIdx.x;
    int blk=blockIdx.x;
    int F=ws[O_FLAG]>0.5f;
    float rsb=ws[O_BRS];

    float wrfreg[20];
    #pragma unroll
    for(int u=0;u<20;u++){
        int idx=t+256*u;
        int f=idx>>6, k=idx&63;
        wrfreg[u]=ws[O_WRF+(size_t)(512+k)*FF+f];
    }

    for(int idx=t; idx<4096; idx+=256){ int k=idx>>6, c=idx&63; wbuf[k*PSTRIDE+c]=ws[O_WPR2+idx]; }
    for(int idx=t; idx<512; idx+=256) w1s[idx]=ws[O_WPR1+idx];
    for(int idx=t; idx<512; idx+=256) bbs[idx]=LDI(bbox,(size_t)blk*512+idx,F);
    if(t<64){
        b1s[t]=ws[O_BPR1+t]; g1s[t]=ws[O_GPR+t]; be1s[t]=ws[O_EPR+t];
        b2s[t]=ws[O_BPR2+t]; wrss[t]=ws[O_WRS+512+t];
    } else if(t<144){
        brfs[t-64]=ws[O_BRF+t-64];
    }
    if(t<64){
        int p=blk*64+t;
        int r=p/NN, j=p-r*NN;
        int b=r/NN, i=r-b*NN;
        int dg=(i==j);
        rowmi[t]=ws[O_MF+r];
        rowmj[t]=ws[O_MF+b*NN+j];
        rowdg[t]=dg;
        rowbase[t]=dg? ws[O_SS+r] : ws[O_SO+b*NN+j];
        rowfb[t]=dg? (O_FS+r*FF) : (O_FO+(b*NN+j)*FF);
        rowps[t]=O_PS+r*PD;
    }
    __syncthreads();

    int wv=t>>6, ln=t&63;
    #pragma unroll 2
    for(int q=0;q<16;q++){
        int m=wv*16+q;
        float acc=0.f;
        #pragma unroll
        for(int u=0;u<8;u++) acc+=bbs[m*8+u]*w1s[u*64+ln];
        float h1=fmaxf(acc+b1s[ln],0.f);
        float sm=h1;
        for(int o=32;o>0;o>>=1) sm+=__shfl_xor(sm,o,64);
        float mean=sm*(1.f/64.f);
        float d=h1-mean;
        float vv=d*d;
        for(int o=32;o>0;o>>=1) vv+=__shfl_xor(vv,o,64);
        float rstd=rsqrtf(vv*(1.f/64.f)+1e-5f);
        zp[ZROW(m)+ln]=d*rstd*g1s[ln]+be1s[ln];
    }
    // NO barrier: GEMM1 reads only own-wave zp rows + pre-staged wbuf.

    int tr=t>>4, tc=t&15;
    int m0=tr*4, c0=tc*4;
    float a1[4][4]={};
    #pragma unroll 2
    for(int k0=0;k0<64;k0+=4){
        float4 zv[4], wvv[4];
        #pragma unroll
        for(int i=0;i<4;i++) zv[i]=*(const float4*)&zp[ZROW(m0+i)+k0];
        #pragma unroll
        for(int u=0;u<4;u++) wvv[u]=*(const float4*)&wbuf[(k0+u)*PSTRIDE+c0];
        #pragma unroll
        for(int i=0;i<4;i++){
            const float* zpp=(const float*)&zv[i];
            #pragma unroll
            for(int u=0;u<4;u++){
                const float* wp=(const float*)&wvv[u];
                float zk=zpp[u];
                a1[i][0]+=zk*wp[0]; a1[i][1]+=zk*wp[1];
                a1[i][2]+=zk*wp[2]; a1[i][3]+=zk*wp[3];
            }
        }
    }
    __syncthreads();

    #pragma unroll
    for(int i=0;i<4;i++){
        int m=m0+i;
        float4 o;
        if(rowdg[m]){
            const float* ps=ws+rowps[m];
            float sc=rowmi[m];           // deferred pos_self mask (mf in {0,1})
            o.x=ps[c0]*sc; o.y=ps[c0+1]*sc; o.z=ps[c0+2]*sc; o.w=ps[c0+3]*sc;
        } else {
            float sc=rowmi[m]*rowmj[m];
            o.x=fmaxf(a1[i][0]+b2s[c0+0],0.f)*sc;
            o.y=fmaxf(a1[i][1]+b2s[c0+1],0.f)*sc;
            o.z=fmaxf(a1[i][2]+b2s[c0+2],0.f)*sc;
            o.w=fmaxf(a1[i][3]+b2s[c0+3],0.f)*sc;
        }
        *(float4*)&zp[ZROW(m)+c0]=o;
    }

    #pragma unroll 2
    for(int q=0;q<16;q++){
        int m=wv*16+q;
        float lp=zp[ZROW(m)+ln]*wrss[ln];
        for(int o=32;o>0;o>>=1) lp+=__shfl_xor(lp,o,64);
        if(ln==0){
            ws[O_LG+(size_t)blk*64+m]=rowmi[m]*rowbase[m]+lp+rsb;
        }
    }

    #pragma unroll
    for(int u=0;u<20;u++){
        int idx=t+256*u;
        wbuf[(idx>>6)*PSTRIDE+(idx&63)]=wrfreg[u];
    }
    __syncthreads();

    {
        int c5=tc*5;
        float a2[4][5]={};
        #pragma unroll 2
        for(int k0=0;k0<64;k0+=4){
            float4 zv[4], wv5[5];
            #pragma unroll
            for(int i=0;i<4;i++) zv[i]=*(const float4*)&zp[ZROW(m0+i)+k0];
            #pragma unroll
            for(int j=0;j<5;j++) wv5[j]=*(const float4*)&wbuf[(c5+j)*PSTRIDE+k0];
            #pragma unroll
            for(int i=0;i<4;i++){
                const float* zpp=(const float*)&zv[i];
                #pragma unroll
                for(int j=0;j<5;j++){
                    const float* wp=(const float*)&wv5[j];
                    a2[i][j]+=zpp[0]*wp[0]+zpp[1]*wp[1]+zpp[2]*wp[2]+zpp[3]*wp[3];
                }
            }
        }
        #pragma unroll
        for(int i=0;i<4;i++){
            int m=m0+i;
            size_t p=(size_t)blk*64+m;
            float mi=rowmi[m];
            const float* fb=ws+rowfb[m];
            #pragma unroll
            for(int j=0;j<5;j++){
                int c=c5+j;
                ws[O_FT+p*FF+c]=fmaxf(mi*fb[c]+a2[i][j]+brfs[c],0.f);
            }
        }
    }
}

// ---------------- k_ra: merged relas (blocks <1600) + adj (blocks >=1600) ----------------
__global__ void __launch_bounds__(256,4) k_ra(float* __restrict__ ws){
    __shared__ float shm[2552];   // relas: attn[64]; adj: Af[2500] + dinv[50]
    int blk=blockIdx.x, t=threadIdx.x;
    if(blk<BN){
        int r=blk;
        int b=r/NN;
        float mi=ws[O_MF+r];
        if(t<64){
            float v=-1e9f;
            if(t<NN){
                float mj=ws[O_MF+b*NN+t];
                bool pm=(mi>0.5f)&&(mj>0.5f);
                v=pm? ws[O_LG+(size_t)r*NN+t] : -1e9f;
            }
            float mx=v;
            for(int o=32;o>0;o>>=1) mx=fmaxf(mx,__shfl_xor(mx,o,64));
            float e=(t<NN)? __expf(v-mx) : 0.f;
            float sm=e;
            for(int o=32;o>0;o>>=1) sm+=__shfl_xor(sm,o,64);
            shm[t]=e*(1.f/sm);
        }
        __syncthreads();
        if(t<FF){
            float s=0.f;
            const float* ft=ws+O_FT+(size_t)r*NN*FF;
            for(int j=0;j<NN;j++) s+=shm[j]*ft[(size_t)j*FF+t];
            ws[O_RL+(size_t)r*FF+t]=s*mi;
        }
    } else {
        int b=blk-BN;
        float* Af=shm;
        float* dinv=shm+2500;
        for(int idx=t; idx<NN*NN; idx+=256){
            int i=idx/NN, j=idx%NN;
            float l=ws[O_LG+(size_t)b*NN*NN+idx];
            bool a=(l>0.f)&&(ws[O_MF+b*NN+i]>0.5f)&&(ws[O_MF+b*NN+j]>0.5f);
            Af[idx]=(a||i==j)?1.f:0.f;
        }
        __syncthreads();
        if(t<NN){
            float dg=0.f;
            for(int i=0;i<NN;i++) dg+=Af[i*NN+t];
            dinv[t]=rsqrtf(dg);
        }
        __syncthreads();
        for(int idx=t; idx<NN*NN; idx+=256){
            int i=idx/NN, j=idx%NN;
            ws[O_AN+(size_t)b*NN*NN+idx]=Af[idx]*dinv[i]*dinv[j];
        }
    }
}

// ---------------- kgcn: fused (An^T X) @ W + bias, relu — replaces kagg+ktf ----------------
// Each block computes its own 5 XX rows (i-ascending accumulation — identical order to
// the old kagg) into LDS, then runs the unchanged 5-row x 256-col GEMM. XX work is
// duplicated x NTILE (tiny); saves 3 launches + the T round-trip. Bit-identical numerics.
__global__ void __launch_bounds__(256,4) kgcn(int mode, float* __restrict__ out,
                   float* __restrict__ ws,
                   const float* __restrict__ W, const float* __restrict__ bias,
                   int K, int NCOL, int NTILE){
    __shared__ float ans[5*50];   // ans[i*5+jj] = An[b][i][j0+jj]
    __shared__ float xs[5*GG];
    int blk=blockIdx.x, t=threadIdx.x;
    int rg=blk/NTILE, tile=blk%NTILE;
    int gr0=rg*5;
    int b=gr0/NN, j0=gr0-b*NN;     // 5 | 50 -> whole group in one batch
    for(int idx=t; idx<250; idx+=256){
        int i=idx/5, jj=idx-i*5;
        ans[idx]=ws[O_AN+(size_t)b*2500+(size_t)i*NN+j0+jj];
    }
    __syncthreads();
    for(int c=t; c<K; c+=256){
        float a0=0.f,a1=0.f,a2=0.f,a3=0.f,a4=0.f;
        for(int i=0;i<NN;i++){
            float xv;
            int r=b*NN+i;
            if(mode==0){
                xv=(c<DD)? out[(size_t)(2*b)*NN*DD+(size_t)i*DD+c]
                         : ws[O_RL+(size_t)r*FF+(c-DD)];
            } else if(mode==1) xv=ws[O_X1+(size_t)r*GG+c];
            else               xv=ws[O_X2+(size_t)r*DD+c];
            const float* ar=&ans[i*5];
            a0+=ar[0]*xv; a1+=ar[1]*xv; a2+=ar[2]*xv; a3+=ar[3]*xv; a4+=ar[4]*xv;
        }
        xs[0*K+c]=a0; xs[1*K+c]=a1; xs[2*K+c]=a2; xs[3*K+c]=a3; xs[4*K+c]=a4;
    }
    __syncthreads();
    int c=tile*256+t;
    if(c>=NCOL) return;
    float acc[5];
    #pragma unroll
    for(int u=0;u<5;u++) acc[u]=0.f;
    for(int k0=0;k0<K;k0+=8){
        float w[8];
        #pragma unroll
        for(int u=0;u<8;u++) w[u]=W[(size_t)(k0+u)*NCOL+c];
        #pragma unroll
        for(int row=0;row<5;row++){
            float4 a0=*(const float4*)&xs[row*K+k0];
            float4 a1=*(const float4*)&xs[row*K+k0+4];
            acc[row]+=a0.x*w[0]; acc[row]+=a0.y*w[1];
            acc[row]+=a0.z*w[2]; acc[row]+=a0.w*w[3];
            acc[row]+=a1.x*w[4]; acc[row]+=a1.y*w[5];
            acc[row]+=a1.z*w[6]; acc[row]+=a1.w*w[7];
        }
    }
    int gr00=rg*5;
    float bc=bias[c];
    #pragma unroll
    for(int u=0;u<5;u++){
        float v=fmaxf(acc[u]+bc,0.f);
        int gr=gr00+u;
        if(mode==0)      ws[O_X1+(size_t)gr*GG+c]=v;
        else if(mode==1) ws[O_X2+(size_t)gr*DD+c]=v;
        else {
            int bb=gr/NN, j=gr-bb*NN;
            out[(size_t)(2*bb+1)*NN*DD+(size_t)j*DD+c]=v;
        }
    }
}

extern "C" void kernel_launch(void* const* d_in, const int* in_sizes, int n_in,
                              void* d_out, int out_size, void* d_ws, size_t ws_size,
                              hipStream_t stream) {
    const bf16* images  = (const bf16*)d_in[0];
    const bf16* selfbbox= (const bf16*)d_in[1];
    const bf16* bbox    = (const bf16*)d_in[2];

    float* out=(float*)d_out;
    float* ws =(float*)d_ws;

    k_flag<<<1,64,0,stream>>>(images, ws);
    kw<<<1024,256,0,stream>>>((const bf16*)d_in[3],(const bf16*)d_in[4],(const bf16*)d_in[5],
                             (const bf16*)d_in[6],(const bf16*)d_in[7],(const bf16*)d_in[8],
                             (const bf16*)d_in[9],(const bf16*)d_in[10],(const bf16*)d_in[11],
                             (const bf16*)d_in[12],(const bf16*)d_in[13],(const bf16*)d_in[14],
                             (const bf16*)d_in[15],(const bf16*)d_in[16],(const bf16*)d_in[17],
                             (const bf16*)d_in[18],(const bf16*)d_in[19],(const bf16*)d_in[20],
                             (const bf16*)d_in[21],(const bf16*)d_in[22],(const bf16*)d_in[23],
                             (const bf16*)d_in[24],(const bf16*)d_in[25],(const bf16*)d_in[26],
                             (const bf16*)d_in[27],(const bf16*)d_in[28],(const bf16*)d_in[29],
                             (const bf16*)d_in[30],(const bf16*)d_in[31],(const bf16*)d_in[32],
                             ws);
    k_x<<<2000,256,0,stream>>>(images, selfbbox, ws);
    k_xr<<<400,256,0,stream>>>(ws, out);
    k_so1<<<1600,256,0,stream>>>(out, ws);
    k_so2<<<800,256,0,stream>>>(ws);
    k_pair<<<1250,256,0,stream>>>(bbox, ws);
    k_ra<<<BN+BB,256,0,stream>>>(ws);

    kgcn<<<320*3,256,0,stream>>>(0, out, ws, ws+O_WG1, ws+O_BG1, GG, GG, 3);
    kgcn<<<320*2,256,0,stream>>>(1, out, ws, ws+O_WG2, ws+O_BG2, GG, DD, 2);
    kgcn<<<320*2,256,0,stream>>>(2, out, ws, ws+O_WG3, ws+O_BG3, DD, DD, 2);
}

// Round 16
// 554.407 us; speedup vs baseline: 1.1480x; 1.1480x over previous
//
#include <hip/hip_runtime.h>
#include <hip/hip_bf16.h>

typedef __hip_bfloat16 bf16;

#define BB 32
#define NN 50
#define DIN 2048
#define DD 512
#define PD 64
#define FF 80
#define GG 592
#define BN (BB*NN)      // 1600

// ---------------- ws layout (f32 words) ----------------
#define O_FLAG  0
#define O_MF    16
#define O_SS    1616
#define O_SO    3216
#define O_PS    4816
#define O_FS    107216
#define O_FO    235216
#define O_RL    363216     // k_relas output; ALSO k_x row-sum partials [1600x8] (dead until k_relas)
#define O_LG    491216     // full logits [1600x50] (f32 — edge threshold)
#define O_AN    571216
#define O_T     651216
#define O_X1    1598416
#define O_X2    2545616
#define O_WPRE  3364816
#define O_BPRE  4413392
#define O_GPRE  4413904
#define O_EPRE  4414416
#define O_WSUBJ 4414928
#define O_BSUBJ 4677072
#define O_WOBJ  4677584
#define O_BOBJ  4939728
#define O_WPS1  4940240
#define O_BPS1  4940752
#define O_GPS   4940816
#define O_EPS   4940880
#define O_WPS2  4940944
#define O_BPS2  4945040
#define O_WPR1  4945104
#define O_BPR1  4945616
#define O_GPR   4945680
#define O_EPR   4945744
#define O_WPR2  4945808
#define O_BPR2  4949904
#define O_WRS   4949968
#define O_BRS   4950544
#define O_WRF   4950560
#define O_BRF   4996640
#define O_WG1   4996736
#define O_BG1   5347200
#define O_WG2   5347792
#define O_BG2   5650896
#define O_WG3   5651408
#define O_BG3   5913552
#define O_FT    5914064    // per-pair feat [80000x80]; ALSO k_x partials + k_so ys scratch

// k_x split-K partials: slice ks<7 at O_FT + ks*819200, slice 7 at O_T
// k_so ys scratch: ys(mat) at O_FT + mat*PSLICE (dead after k_so2, before k_pair writes FT)
#define PSLICE  819200

__device__ __forceinline__ float b2f(bf16 x){ return __bfloat162float(x); }

// Load logical f32 element i of an input buffer (bf16-pair reconstruction when F=1).
__device__ __forceinline__ float LDI(const bf16* p, size_t i, int f32m){
    if(f32m){
        bf16 a=p[2*i], b=p[2*i+1];
        unsigned short lo,hi;
        __builtin_memcpy(&lo,&a,2); __builtin_memcpy(&hi,&b,2);
        unsigned v=((unsigned)hi<<16)|(unsigned)lo;
        float f; __builtin_memcpy(&f,&v,4);
        return f;
    }
    return __bfloat162float(p[i]);
}

// ---------------- flag ----------------
__global__ void k_flag(const bf16* __restrict__ images, float* __restrict__ ws){
    __shared__ int cnt;
    if(threadIdx.x==0) cnt=0;
    __syncthreads();
    bf16 h=images[2*threadIdx.x];
    unsigned short u; __builtin_memcpy(&u,&h,2);
    unsigned e=(u>>7)&0xFF;
    int sane=((u&0x7FFF)==0 || (e>=0x70&&e<=0x85))?1:0;
    atomicAdd(&cnt,sane);
    __syncthreads();
    if(threadIdx.x==0) ws[O_FLAG]=(cnt<48)?1.f:0.f;
}

// ---------------- kw: convert all weights to f32 in ws ----------------
__device__ __forceinline__ void conv(const bf16* s, float* d, int n, int F, int i0, int st){
    for(int g=i0; g<n; g+=st) d[g]=LDI(s,(size_t)g,F);
}
__global__ void kw(const bf16* p0,const bf16* p1,const bf16* p2,const bf16* p3,
                   const bf16* p4,const bf16* p5,const bf16* p6,const bf16* p7,
                   const bf16* p8,const bf16* p9,const bf16* p10,const bf16* p11,
                   const bf16* p12,const bf16* p13,const bf16* p14,const bf16* p15,
                   const bf16* p16,const bf16* p17,const bf16* p18,const bf16* p19,
                   const bf16* p20,const bf16* p21,const bf16* p22,const bf16* p23,
                   const bf16* p24,const bf16* p25,const bf16* p26,const bf16* p27,
                   const bf16* p28,const bf16* p29, float* __restrict__ ws){
    int F=ws[O_FLAG]>0.5f;
    int i0=blockIdx.x*256+threadIdx.x, st=gridDim.x*256;
    conv(p0, ws+O_WPRE, 1048576,F,i0,st);
    conv(p1, ws+O_BPRE, 512,F,i0,st);
    conv(p2, ws+O_GPRE, 512,F,i0,st);
    conv(p3, ws+O_EPRE, 512,F,i0,st);
    conv(p4, ws+O_WSUBJ,262144,F,i0,st);
    conv(p5, ws+O_BSUBJ,512,F,i0,st);
    conv(p6, ws+O_WOBJ, 262144,F,i0,st);
    conv(p7, ws+O_BOBJ, 512,F,i0,st);
    conv(p8, ws+O_WPS1, 512,F,i0,st);
    conv(p9, ws+O_BPS1, 64,F,i0,st);
    conv(p10,ws+O_GPS,  64,F,i0,st);
    conv(p11,ws+O_EPS,  64,F,i0,st);
    conv(p12,ws+O_WPS2, 4096,F,i0,st);
    conv(p13,ws+O_BPS2, 64,F,i0,st);
    conv(p14,ws+O_WPR1, 512,F,i0,st);
    conv(p15,ws+O_BPR1, 64,F,i0,st);
    conv(p16,ws+O_GPR,  64,F,i0,st);
    conv(p17,ws+O_EPR,  64,F,i0,st);
    conv(p18,ws+O_WPR2, 4096,F,i0,st);
    conv(p19,ws+O_BPR2, 64,F,i0,st);
    conv(p20,ws+O_WRS,  576,F,i0,st);
    conv(p21,ws+O_BRS,  1,F,i0,st);
    conv(p22,ws+O_WRF,  46080,F,i0,st);
    conv(p23,ws+O_BRF,  80,F,i0,st);
    conv(p24,ws+O_WG1,  350464,F,i0,st);
    conv(p25,ws+O_BG1,  592,F,i0,st);
    conv(p26,ws+O_WG2,  303104,F,i0,st);
    conv(p27,ws+O_BG2,  512,F,i0,st);
    conv(p28,ws+O_WG3,  262144,F,i0,st);
    conv(p29,ws+O_BG3,  512,F,i0,st);
}

// ---------------- k_x: split-K x-GEMM + fused image row-sum partials (k_mask folded) ----------------
__global__ void __launch_bounds__(256,4) k_x(const bf16* __restrict__ images,
                                             float* __restrict__ ws){
    __shared__ float as[8*256];      // 8 KB
    __shared__ float rsum[4][8];
    int blk=blockIdx.x, t=threadIdx.x;
    int rg=blk>>3, ks=blk&7;
    int r0=rg*8, kbase=ks*256;
    int F=ws[O_FLAG]>0.5f;
    int wv=t>>6, ln=t&63;
    float sv[8];
    #pragma unroll
    for(int row=0;row<8;row++){
        float v=LDI(images,(size_t)(r0+row)*DIN+kbase+t,F);
        as[row*256+t]=v;
        sv[row]=v;
    }
    #pragma unroll
    for(int row=0;row<8;row++){
        float s=sv[row];
        for(int m=32;m>0;m>>=1) s+=__shfl_xor(s,m,64);
        sv[row]=s;
    }
    if(ln==0){
        #pragma unroll
        for(int row=0;row<8;row++) rsum[wv][row]=sv[row];
    }
    __syncthreads();
    if(t<8){
        float s=rsum[0][t]+rsum[1][t]+rsum[2][t]+rsum[3][t];
        ws[O_RL+(size_t)(r0+t)*8+ks]=s;
    }
    const float* wP=ws+O_WPRE+(size_t)kbase*DD;
    int c0=t, c1=t+256;
    float acc[8][2]={};
    for(int k0=0;k0<256;k0+=8){
        float w0[8],w1[8];
        #pragma unroll
        for(int u=0;u<8;u++){ w0[u]=wP[(size_t)(k0+u)*DD+c0]; w1[u]=wP[(size_t)(k0+u)*DD+c1]; }
        #pragma unroll
        for(int row=0;row<8;row++){
            float4 a0=*(const float4*)&as[row*256+k0];
            float4 a1=*(const float4*)&as[row*256+k0+4];
            acc[row][0]+=a0.x*w0[0]; acc[row][1]+=a0.x*w1[0];
            acc[row][0]+=a0.y*w0[1]; acc[row][1]+=a0.y*w1[1];
            acc[row][0]+=a0.z*w0[2]; acc[row][1]+=a0.z*w1[2];
            acc[row][0]+=a0.w*w0[3]; acc[row][1]+=a0.w*w1[3];
            acc[row][0]+=a1.x*w0[4]; acc[row][1]+=a1.x*w1[4];
            acc[row][0]+=a1.y*w0[5]; acc[row][1]+=a1.y*w1[5];
            acc[row][0]+=a1.z*w0[6]; acc[row][1]+=a1.z*w1[6];
            acc[row][0]+=a1.w*w0[7]; acc[row][1]+=a1.w*w1[7];
        }
    }
    float* P=ws + ((ks<7)? (O_FT+(size_t)ks*PSLICE) : (size_t)O_T);
    #pragma unroll
    for(int row=0;row<8;row++){
        size_t b=(size_t)(r0+row)*DD;
        P[b+c0]=acc[row][0]; P[b+c1]=acc[row][1];
    }
}

// ---------------- k_xr: reduce partials + bias + relu + LN -> x; finalize mask ----------------
__global__ void __launch_bounds__(256,4) k_xr(float* __restrict__ ws, float* __restrict__ out){
    __shared__ float red[256];
    int blk=blockIdx.x, t=threadIdx.x;
    int r0=blk*4;
    if(t<4){
        int r=r0+t;
        float s=0.f;
        for(int ks=0;ks<8;ks++) s+=ws[O_RL+(size_t)r*8+ks];
        float mf=(s!=0.f)?1.f:0.f;
        ws[O_MF+r]=mf;
        out[(size_t)BB*2*NN*DD+r]=1.f-mf;
    }
    const float* bPre=ws+O_BPRE; const float* gPre=ws+O_GPRE; const float* ePre=ws+O_EPRE;
    int c0=t, c1=t+256;
    for(int row=0;row<4;row++){
        int r=r0+row;
        float y0=bPre[c0], y1=bPre[c1];
        for(int ks=0;ks<8;ks++){
            const float* P=ws + ((ks<7)? (O_FT+(size_t)ks*PSLICE) : (size_t)O_T);
            y0+=P[(size_t)r*DD+c0]; y1+=P[(size_t)r*DD+c1];
        }
        y0=fmaxf(y0,0.f); y1=fmaxf(y1,0.f);
        red[t]=y0+y1; __syncthreads();
        for(int o=128;o>0;o>>=1){ if(t<o) red[t]+=red[t+o]; __syncthreads(); }
        float mean=red[0]/DD; __syncthreads();
        float d0=y0-mean, d1=y1-mean;
        red[t]=d0*d0+d1*d1; __syncthreads();
        for(int o=128;o>0;o>>=1){ if(t<o) red[t]+=red[t+o]; __syncthreads(); }
        float rstd=rsqrtf(red[0]/DD+1e-5f);
        __syncthreads();
        float xv0=d0*rstd*gPre[c0]+ePre[c0];
        float xv1=d1*rstd*gPre[c1]+ePre[c1];
        size_t ob=((size_t)(r/NN)*2)*NN*DD+(size_t)(r%NN)*DD;
        out[ob+c0]=xv0; out[ob+c1]=xv1;
    }
}

// ---------------- k_so1: subj/obj GEMM, col-split, float4 LDS reads ----------------
__global__ void __launch_bounds__(256,4) k_so1(const float* __restrict__ out,
                                               float* __restrict__ ws){
    __shared__ float xs[4*DD];   // 8 KB
    __shared__ float mrow_s[4];
    int blk=blockIdx.x, t=threadIdx.x;
    int rg=blk>>2, mat=(blk>>1)&1, ch=blk&1;
    int r0=rg*4;
    for(int idx=t; idx<4*DD; idx+=256){
        int row=idx>>9, k=idx&511;
        int r=r0+row;
        xs[idx]=out[((size_t)(r/NN)*2)*NN*DD+(size_t)(r%NN)*DD+k];
    }
    if(t<4) mrow_s[t]=ws[O_MF+r0+t];
    __syncthreads();
    const float* W =ws+(mat?O_WOBJ:O_WSUBJ);
    const float* Bb=ws+(mat?O_BOBJ:O_BSUBJ);
    int c=ch*256+t;
    float acc[4]={0.f,0.f,0.f,0.f};
    for(int k0=0;k0<DD;k0+=8){
        float w[8];
        #pragma unroll
        for(int u=0;u<8;u++) w[u]=W[(size_t)(k0+u)*DD+c];
        #pragma unroll
        for(int row=0;row<4;row++){
            float4 a0=*(const float4*)&xs[row*DD+k0];
            float4 a1=*(const float4*)&xs[row*DD+k0+4];
            acc[row]+=a0.x*w[0]; acc[row]+=a0.y*w[1];
            acc[row]+=a0.z*w[2]; acc[row]+=a0.w*w[3];
            acc[row]+=a1.x*w[4]; acc[row]+=a1.y*w[5];
            acc[row]+=a1.z*w[6]; acc[row]+=a1.w*w[7];
        }
    }
    float* Y=ws+O_FT+(size_t)mat*PSLICE;
    #pragma unroll
    for(int row=0;row<4;row++)
        Y[(size_t)(r0+row)*DD+c]=fmaxf(acc[row]+Bb[c],0.f)*mrow_s[row];
}

// ---------------- k_so2: rs dots + rf projections, float4 LDS reads ----------------
__global__ void __launch_bounds__(256,4) k_so2(float* __restrict__ ws){
    __shared__ float yl[4][DD];  // 8 KB
    int blk=blockIdx.x, t=threadIdx.x, wv=t>>6, ln=t&63;
    int combo=blk*4+wv;
    int mat=combo&1, r=combo>>1;
    const float* Y=ws+O_FT+(size_t)mat*PSLICE+(size_t)r*DD;
    for(int k=ln;k<DD;k+=64) yl[wv][k]=Y[k];
    __syncthreads();
    const float* wRs=ws+O_WRS;
    float ps=0.f;
    for(int k=ln;k<DD;k+=64) ps+=yl[wv][k]*wRs[k];
    for(int m=32;m>0;m>>=1) ps+=__shfl_xor(ps,m,64);
    if(ln==0) ws[(mat?O_SO:O_SS)+r]=ps;
    const float* wRf=ws+O_WRF;
    float* dst=ws+(mat?O_FO:O_FS)+(size_t)r*FF;
    {
        float a=0.f;
        for(int k0=0;k0<DD;k0+=4){
            float4 y4=*(const float4*)&yl[wv][k0];
            a+=y4.x*wRf[(size_t)k0*FF+ln];
            a+=y4.y*wRf[(size_t)(k0+1)*FF+ln];
            a+=y4.z*wRf[(size_t)(k0+2)*FF+ln];
            a+=y4.w*wRf[(size_t)(k0+3)*FF+ln];
        }
        dst[ln]=a;
    }
    if(ln<16){
        int c=64+ln;
        float a=0.f;
        for(int k0=0;k0<DD;k0+=4){
            float4 y4=*(const float4*)&yl[wv][k0];
            a+=y4.x*wRf[(size_t)k0*FF+c];
            a+=y4.y*wRf[(size_t)(k0+1)*FF+c];
            a+=y4.z*wRf[(size_t)(k0+2)*FF+c];
            a+=y4.w*wRf[(size_t)(k0+3)*FF+c];
        }
        dst[c]=a;
    }
}

// ---------------- k_pos_self ----------------
__global__ void k_pos_self(const bf16* __restrict__ sb, float* __restrict__ ws){
    __shared__ float h[PD];
    __shared__ float stat[2];
    int r=blockIdx.x, t=threadIdx.x;
    int F=ws[O_FLAG]>0.5f;
    const float* w1=ws+O_WPS1;
    float acc=0.f;
    for(int q=0;q<8;q++) acc+=LDI(sb,(size_t)r*8+q,F)*w1[q*PD+t];
    acc=fmaxf(acc+ws[O_BPS1+t],0.f);
    h[t]=acc; __syncthreads();
    if(t==0){
        float sm=0; for(int k=0;k<PD;k++) sm+=h[k];
        float mean=sm/PD;
        float v=0; for(int k=0;k<PD;k++){float d=h[k]-mean; v+=d*d;}
        stat[0]=mean; stat[1]=rsqrtf(v/PD+1e-5f);
    }
    __syncthreads();
    float hn=(acc-stat[0])*stat[1]*ws[O_GPS+t]+ws[O_EPS+t];
    h[t]=hn; __syncthreads();
    float a2=0.f;
    const float* w2=ws+O_WPS2;
    for(int k=0;k<PD;k++) a2+=h[k]*w2[k*PD+t];
    ws[O_PS+(size_t)r*PD+t]=fmaxf(a2+ws[O_BPS2+t],0.f)*ws[O_MF+r];
}

// ---------------- k_pair: R5 structure + barrier elision + phase overlap (77.7us measured) ----------------
#define PSTRIDE 68
#define ZROW(m) ((m)*PSTRIDE + (((m)>>3)<<2))

__global__ void __launch_bounds__(256,3) k_pair(const bf16* __restrict__ bbox,
                                                float* __restrict__ ws){
    __shared__ float zp[64*PSTRIDE+64];    // z, then pv (17.5 KB)
    __shared__ float wbuf[80*PSTRIDE];     // W2t [k][c], then WrfT [f][k] (21.25 KB)
    __shared__ float w1s[512];
    __shared__ float bbs[512];
    __shared__ float b1s[64], g1s[64], be1s[64], b2s[64], wrss[64];
    __shared__ float brfs[80];
    __shared__ float rowmi[64], rowmj[64], rowbase[64];
    __shared__ int   rowfb[64], rowps[64], rowdg[64];

    int t=threadIdx.x;
    int blk=blockIdx.x;
    int F=ws[O_FLAG]>0.5f;
    float rsb=ws[O_BRS];

    // WrfT prefetch into regs (LDS-written in phase D; latency hidden under z+GEMM1)
    float wrfreg[20];
    #pragma unroll
    for(int u=0;u<20;u++){
        int idx=t+256*u;
        int f=idx>>6, k=idx&63;
        wrfreg[u]=ws[O_WRF+(size_t)(512+k)*FF+f];
    }

    // ---- stage ----
    for(int idx=t; idx<4096; idx+=256){ int k=idx>>6, c=idx&63; wbuf[k*PSTRIDE+c]=ws[O_WPR2+idx]; }
    for(int idx=t; idx<512; idx+=256) w1s[idx]=ws[O_WPR1+idx];
    for(int idx=t; idx<512; idx+=256) bbs[idx]=LDI(bbox,(size_t)blk*512+idx,F);
    if(t<64){
        b1s[t]=ws[O_BPR1+t]; g1s[t]=ws[O_GPR+t]; be1s[t]=ws[O_EPR+t];
        b2s[t]=ws[O_BPR2+t]; wrss[t]=ws[O_WRS+512+t];
    } else if(t<144){
        brfs[t-64]=ws[O_BRF+t-64];
    }
    if(t<64){
        int p=blk*64+t;
        int r=p/NN, j=p-r*NN;
        int b=r/NN, i=r-b*NN;
        int dg=(i==j);
        rowmi[t]=ws[O_MF+r];
        rowmj[t]=ws[O_MF+b*NN+j];
        rowdg[t]=dg;
        rowbase[t]=dg? ws[O_SS+r] : ws[O_SO+b*NN+j];
        rowfb[t]=dg? (O_FS+r*FF) : (O_FO+(b*NN+j)*FF);
        rowps[t]=O_PS+r*PD;
    }
    __syncthreads();

    // ---- z-phase: bbox MLP + LN, wave-serial over 16 pairs/wave (unroll-2 for ILP) ----
    int wv=t>>6, ln=t&63;
    #pragma unroll 2
    for(int q=0;q<16;q++){
        int m=wv*16+q;
        float acc=0.f;
        #pragma unroll
        for(int u=0;u<8;u++) acc+=bbs[m*8+u]*w1s[u*64+ln];
        float h1=fmaxf(acc+b1s[ln],0.f);
        float sm=h1;
        for(int o=32;o>0;o>>=1) sm+=__shfl_xor(sm,o,64);
        float mean=sm*(1.f/64.f);
        float d=h1-mean;
        float vv=d*d;
        for(int o=32;o>0;o>>=1) vv+=__shfl_xor(vv,o,64);
        float rstd=rsqrtf(vv*(1.f/64.f)+1e-5f);
        zp[ZROW(m)+ln]=d*rstd*g1s[ln]+be1s[ln];
    }
    // NO barrier: GEMM1 reads only own-wave zp rows + pre-staged wbuf.

    // ---- GEMM1 (in regs): a1 = z @ W2, 4x4 tiles ----
    int tr=t>>4, tc=t&15;
    int m0=tr*4, c0=tc*4;
    float a1[4][4]={};
    #pragma unroll 2
    for(int k0=0;k0<64;k0+=4){
        float4 zv[4], wvv[4];
        #pragma unroll
        for(int i=0;i<4;i++) zv[i]=*(const float4*)&zp[ZROW(m0+i)+k0];
        #pragma unroll
        for(int u=0;u<4;u++) wvv[u]=*(const float4*)&wbuf[(k0+u)*PSTRIDE+c0];
        #pragma unroll
        for(int i=0;i<4;i++){
            const float* zpp=(const float*)&zv[i];
            #pragma unroll
            for(int u=0;u<4;u++){
                const float* wp=(const float*)&wvv[u];
                float zk=zpp[u];
                a1[i][0]+=zk*wp[0]; a1[i][1]+=zk*wp[1];
                a1[i][2]+=zk*wp[2]; a1[i][3]+=zk*wp[3];
            }
        }
    }
    __syncthreads();   // all waves' GEMM1 reads of wbuf (W2t) complete -> wbuf reusable

    // ---- phase D: pv (relu*mask, fused diag override) over zp (own-wave rows) ----
    #pragma unroll
    for(int i=0;i<4;i++){
        int m=m0+i;
        float4 o;
        if(rowdg[m]){
            const float* ps=ws+rowps[m];
            o.x=ps[c0]; o.y=ps[c0+1]; o.z=ps[c0+2]; o.w=ps[c0+3];
        } else {
            float sc=rowmi[m]*rowmj[m];
            o.x=fmaxf(a1[i][0]+b2s[c0+0],0.f)*sc;
            o.y=fmaxf(a1[i][1]+b2s[c0+1],0.f)*sc;
            o.z=fmaxf(a1[i][2]+b2s[c0+2],0.f)*sc;
            o.w=fmaxf(a1[i][3]+b2s[c0+3],0.f)*sc;
        }
        *(float4*)&zp[ZROW(m)+c0]=o;
    }

    // ---- logits (own-wave pv rows; overlap with WrfT stores; exact xor tree) ----
    #pragma unroll 2
    for(int q=0;q<16;q++){
        int m=wv*16+q;
        float lp=zp[ZROW(m)+ln]*wrss[ln];
        for(int o=32;o>0;o>>=1) lp+=__shfl_xor(lp,o,64);
        if(ln==0){
            ws[O_LG+(size_t)blk*64+m]=rowmi[m]*rowbase[m]+lp+rsb;
        }
    }

    // ---- WrfT regs -> LDS ----
    #pragma unroll
    for(int u=0;u<20;u++){
        int idx=t+256*u;
        wbuf[(idx>>6)*PSTRIDE+(idx&63)]=wrfreg[u];
    }
    __syncthreads();

    // ---- GEMM2: ft = relu(mi*fb + pv @ Wrf + brf), 4x5 tiles ----
    {
        int c5=tc*5;
        float a2[4][5]={};
        #pragma unroll 2
        for(int k0=0;k0<64;k0+=4){
            float4 zv[4], wv5[5];
            #pragma unroll
            for(int i=0;i<4;i++) zv[i]=*(const float4*)&zp[ZROW(m0+i)+k0];
            #pragma unroll
            for(int j=0;j<5;j++) wv5[j]=*(const float4*)&wbuf[(c5+j)*PSTRIDE+k0];
            #pragma unroll
            for(int i=0;i<4;i++){
                const float* zpp=(const float*)&zv[i];
                #pragma unroll
                for(int j=0;j<5;j++){
                    const float* wp=(const float*)&wv5[j];
                    a2[i][j]+=zpp[0]*wp[0]+zpp[1]*wp[1]+zpp[2]*wp[2]+zpp[3]*wp[3];
                }
            }
        }
        #pragma unroll
        for(int i=0;i<4;i++){
            int m=m0+i;
            size_t p=(size_t)blk*64+m;
            float mi=rowmi[m];
            const float* fb=ws+rowfb[m];
            #pragma unroll
            for(int j=0;j<5;j++){
                int c=c5+j;
                ws[O_FT+p*FF+c]=fmaxf(mi*fb[c]+a2[i][j]+brfs[c],0.f);
            }
        }
    }
}

// ---------------- k_relas: exact masked softmax (wave-parallel) + feat pooling ----------------
__global__ void k_relas(float* __restrict__ ws){
    __shared__ float attn[64];
    int r=blockIdx.x, t=threadIdx.x;
    int b=r/NN;
    float mi=ws[O_MF+r];
    if(t<64){
        float v=-1e9f;
        if(t<NN){
            float mj=ws[O_MF+b*NN+t];
            bool pm=(mi>0.5f)&&(mj>0.5f);
            v=pm? ws[O_LG+(size_t)r*NN+t] : -1e9f;
        }
        float mx=v;
        for(int o=32;o>0;o>>=1) mx=fmaxf(mx,__shfl_xor(mx,o,64));
        float e=(t<NN)? __expf(v-mx) : 0.f;
        float sm=e;
        for(int o=32;o>0;o>>=1) sm+=__shfl_xor(sm,o,64);
        attn[t]=e*(1.f/sm);
    }
    __syncthreads();
    if(t<FF){
        float s=0.f;
        const float* ft=ws+O_FT+(size_t)r*NN*FF;
        for(int j=0;j<NN;j++) s+=attn[j]*ft[(size_t)j*FF+t];
        ws[O_RL+(size_t)r*FF+t]=s*mi;
    }
}

// ---------------- k_adj: Af from logits + mf ----------------
__global__ void k_adj(float* __restrict__ ws){
    __shared__ float Af[NN*NN];
    __shared__ float dinv[NN];
    int b=blockIdx.x, t=threadIdx.x;
    for(int idx=t; idx<NN*NN; idx+=256){
        int i=idx/NN, j=idx%NN;
        float l=ws[O_LG+(size_t)b*NN*NN+idx];
        bool a=(l>0.f)&&(ws[O_MF+b*NN+i]>0.5f)&&(ws[O_MF+b*NN+j]>0.5f);
        Af[idx]=(a||i==j)?1.f:0.f;
    }
    __syncthreads();
    if(t<NN){
        float dg=0.f;
        for(int i=0;i<NN;i++) dg+=Af[i*NN+t];
        dinv[t]=rsqrtf(dg);
    }
    __syncthreads();
    for(int idx=t; idx<NN*NN; idx+=256){
        int i=idx/NN, j=idx%NN;
        ws[O_AN+(size_t)b*NN*NN+idx]=Af[idx]*dinv[i]*dinv[j];
    }
}

// ---------------- kt: T = X @ W (5-row tiles, float4 LDS reads, unroll-8 W prefetch) ----------------
__global__ void __launch_bounds__(256,4) kt(int mode, const float* __restrict__ out,
                   const float* __restrict__ ws,
                   const float* __restrict__ W, float* __restrict__ T,
                   int K, int NCOL, int NTILE){
    __shared__ float xs[5*GG];
    int blk=blockIdx.x, t=threadIdx.x;
    int rg=blk/NTILE, tile=blk%NTILE;
    for(int idx=t; idx<5*K; idx+=256){
        int row=idx/K, k=idx-row*K;
        int gr=rg*5+row;
        float v;
        if(mode==0){
            int bb=gr/NN, ii=gr-bb*NN;
            if(k<DD) v=out[(size_t)(2*bb)*NN*DD+(size_t)ii*DD+k];
            else     v=ws[O_RL+(size_t)gr*FF+(k-DD)];
        } else if(mode==1) v=ws[O_X1+(size_t)gr*GG+k];
        else               v=ws[O_X2+(size_t)gr*DD+k];
        xs[row*K+k]=v;
    }
    __syncthreads();
    int c=tile*256+t;
    if(c>=NCOL) return;
    float acc[5];
    #pragma unroll
    for(int u=0;u<5;u++) acc[u]=0.f;
    for(int k0=0;k0<K;k0+=8){
        float w[8];
        #pragma unroll
        for(int u=0;u<8;u++) w[u]=W[(size_t)(k0+u)*NCOL+c];
        #pragma unroll
        for(int row=0;row<5;row++){
            float4 a0=*(const float4*)&xs[row*K+k0];
            float4 a1=*(const float4*)&xs[row*K+k0+4];
            acc[row]+=a0.x*w[0]; acc[row]+=a0.y*w[1];
            acc[row]+=a0.z*w[2]; acc[row]+=a0.w*w[3];
            acc[row]+=a1.x*w[4]; acc[row]+=a1.y*w[5];
            acc[row]+=a1.z*w[6]; acc[row]+=a1.w*w[7];
        }
    }
    int gr0=rg*5;
    #pragma unroll
    for(int u=0;u<5;u++) T[(size_t)(gr0+u)*NCOL+c]=acc[u];
}

// ---------------- ka: aggregation ----------------
__global__ void ka(int mode, float* __restrict__ ws, const float* __restrict__ bias,
                   float* __restrict__ out, int NCOL){
    __shared__ float acol[NN];
    int rj=blockIdx.x, t=threadIdx.x;
    int b=rj/NN, j=rj-b*NN;
    if(t<NN) acol[t]=ws[O_AN+(size_t)b*NN*NN+t*NN+j];
    __syncthreads();
    const float* Tb=ws+O_T+(size_t)b*NN*NCOL;
    for(int c=t;c<NCOL;c+=256){
        float acc=0.f;
        for(int i2=0;i2<NN;i2++) acc+=acol[i2]*Tb[(size_t)i2*NCOL+c];
        float v=fmaxf(acc+bias[c],0.f);
        if(mode==2)      out[(size_t)(2*b+1)*NN*DD+(size_t)j*DD+c]=v;
        else if(mode==1) ws[O_X2+(size_t)rj*DD+c]=v;
        else             ws[O_X1+(size_t)rj*GG+c]=v;
    }
}

extern "C" void kernel_launch(void* const* d_in, const int* in_sizes, int n_in,
                              void* d_out, int out_size, void* d_ws, size_t ws_size,
                              hipStream_t stream) {
    const bf16* images  = (const bf16*)d_in[0];
    const bf16* selfbbox= (const bf16*)d_in[1];
    const bf16* bbox    = (const bf16*)d_in[2];

    float* out=(float*)d_out;
    float* ws =(float*)d_ws;

    k_flag<<<1,64,0,stream>>>(images, ws);
    kw<<<512,256,0,stream>>>((const bf16*)d_in[3],(const bf16*)d_in[4],(const bf16*)d_in[5],
                             (const bf16*)d_in[6],(const bf16*)d_in[7],(const bf16*)d_in[8],
                             (const bf16*)d_in[9],(const bf16*)d_in[10],(const bf16*)d_in[11],
                             (const bf16*)d_in[12],(const bf16*)d_in[13],(const bf16*)d_in[14],
                             (const bf16*)d_in[15],(const bf16*)d_in[16],(const bf16*)d_in[17],
                             (const bf16*)d_in[18],(const bf16*)d_in[19],(const bf16*)d_in[20],
                             (const bf16*)d_in[21],(const bf16*)d_in[22],(const bf16*)d_in[23],
                             (const bf16*)d_in[24],(const bf16*)d_in[25],(const bf16*)d_in[26],
                             (const bf16*)d_in[27],(const bf16*)d_in[28],(const bf16*)d_in[29],
                             (const bf16*)d_in[30],(const bf16*)d_in[31],(const bf16*)d_in[32],
                             ws);
    k_x<<<1600,256,0,stream>>>(images, ws);
    k_xr<<<400,256,0,stream>>>(ws, out);
    k_pos_self<<<BN,PD,0,stream>>>(selfbbox, ws);
    k_so1<<<1600,256,0,stream>>>(out, ws);
    k_so2<<<800,256,0,stream>>>(ws);
    k_pair<<<1250,256,0,stream>>>(bbox, ws);
    k_relas<<<BN,128,0,stream>>>(ws);
    k_adj<<<BB,256,0,stream>>>(ws);

    kt<<<320*3,256,0,stream>>>(0, out, ws, ws+O_WG1, ws+O_T, GG, GG, 3);
    ka<<<BN,256,0,stream>>>(0, ws, ws+O_BG1, out, GG);
    kt<<<320*2,256,0,stream>>>(1, out, ws, ws+O_WG2, ws+O_T, GG, DD, 2);
    ka<<<BN,256,0,stream>>>(1, ws, ws+O_BG2, out, DD);
    kt<<<320*2,256,0,stream>>>(2, out, ws, ws+O_WG3, ws+O_T, DD, DD, 2);
    ka<<<BN,256,0,stream>>>(2, ws, ws+O_BG3, out, DD);
}